// Round 6
// baseline (367.753 us; speedup 1.0000x reference)
//
#include <hip/hip_runtime.h>

#define B_ 4
#define C_ 4
#define V_ 262144
#define F_ 64
#define K_ 100
#define THETA 0.9f
#define TAU_ 0.1f
#define CAP2 4096

typedef unsigned long long ull;

// ---------------- workspace layout (bytes) ----------------
// cs     : 0       .. 1024     (C*F floats, [c][f])
// cnt    : 1024    .. 1040     (C floats)
// hist1  : 2048    .. 6144     (B*256 u32)
// hist2  : 6144    .. 10240    (B*256 u32)
// ctrl1  : 10240   .. 10272    (B*2 u32: T1, n_above)
// ctrl2  : 10272   .. 10304    (B*2 u32: P16, n_above2)
// ccount : 10304   .. 10320    (B u32)
// idxout : 10368   .. 11968    (B*K u32)
// cbits  : 16384   .. 81920    (B*CAP2 u32)
// cidx   : 81920   .. 147456   (B*CAP2 u32)
// wbits  : 1048576 .. 5242880  (B*V u32 — product weights' float bits)
// mask16 : 5242880 .. 5767168  (B*V/4 u16 — packed 4-bit class masks per float4)

__global__ void k_init(float* cs, float* cnt, unsigned* hist1, unsigned* hist2, unsigned* ccount) {
    int t = blockIdx.x * blockDim.x + threadIdx.x;
    if (t < C_ * F_) cs[t] = 0.f;
    if (t < C_) cnt[t] = 0.f;
    if (t < B_ * 256) { hist1[t] = 0u; hist2[t] = 0u; }
    if (t < B_) ccount[t] = 0u;
}

// Pack y into 4-bit/v class masks (u16 per float4-group) + class counts.
// y read exactly once, coalesced. grid B*256, block 256, 4 v per thread.
__global__ __launch_bounds__(256) void k_mask(const int* __restrict__ y,
                                              unsigned short* __restrict__ mask16,
                                              float* __restrict__ cnt) {
    int b = blockIdx.x >> 8;
    int i4 = ((blockIdx.x & 255) << 8) | threadIdx.x;   // float4-group in [0, V/4)
    int lane = threadIdx.x & 63;

    const int4* y0 = (const int4*)(y + ((size_t)(b * C_ + 0)) * V_);
    const int4* y1 = (const int4*)(y + ((size_t)(b * C_ + 1)) * V_);
    const int4* y2 = (const int4*)(y + ((size_t)(b * C_ + 2)) * V_);
    const int4* y3 = (const int4*)(y + ((size_t)(b * C_ + 3)) * V_);
    int4 ya = y0[i4], yb = y1[i4], yc = y2[i4], yd = y3[i4];

    // nibble j = class-mask of element j (bit c = class c)
    unsigned n0 = (unsigned)(ya.x > 0) | ((unsigned)(yb.x > 0) << 1) | ((unsigned)(yc.x > 0) << 2) | ((unsigned)(yd.x > 0) << 3);
    unsigned n1 = (unsigned)(ya.y > 0) | ((unsigned)(yb.y > 0) << 1) | ((unsigned)(yc.y > 0) << 2) | ((unsigned)(yd.y > 0) << 3);
    unsigned n2 = (unsigned)(ya.z > 0) | ((unsigned)(yb.z > 0) << 1) | ((unsigned)(yc.z > 0) << 2) | ((unsigned)(yd.z > 0) << 3);
    unsigned n3 = (unsigned)(ya.w > 0) | ((unsigned)(yb.w > 0) << 1) | ((unsigned)(yc.w > 0) << 2) | ((unsigned)(yd.w > 0) << 3);
    mask16[(size_t)b * (V_ / 4) + i4] = (unsigned short)(n0 | (n1 << 4) | (n2 << 8) | (n3 << 12));

    unsigned p01 = ((unsigned)(ya.x > 0) + (ya.y > 0) + (ya.z > 0) + (ya.w > 0))
                 | (((unsigned)(yb.x > 0) + (yb.y > 0) + (yb.z > 0) + (yb.w > 0)) << 16);
    unsigned p23 = ((unsigned)(yc.x > 0) + (yc.y > 0) + (yc.z > 0) + (yc.w > 0))
                 | (((unsigned)(yd.x > 0) + (yd.y > 0) + (yd.z > 0) + (yd.w > 0)) << 16);
    #pragma unroll
    for (int o = 1; o < 64; o <<= 1) {
        p01 += __shfl_xor(p01, o, 64);
        p23 += __shfl_xor(p23, o, 64);
    }
    if (lane == 0) {
        atomicAdd(&cnt[0], (float)(p01 & 0xFFFFu));
        atomicAdd(&cnt[1], (float)(p01 >> 16));
        atomicAdd(&cnt[2], (float)(p23 & 0xFFFFu));
        atomicAdd(&cnt[3], (float)(p23 >> 16));
    }
}

// class_sum[c][f] += emb[b,f,v] * maskbit(c,v).
// One wave per (b, f, 8192-v segment): 8192 waves, 2048 blocks x 4 waves.
// Pure stream: 32 contiguous 1KB wave-loads (8-deep batches), per-thread
// accumulators, NO LDS, NO syncthreads, one shuffle-reduce per wave at end.
__global__ __launch_bounds__(256) void k_class_sum(const float* __restrict__ emb,
                                                   const unsigned short* __restrict__ mask16,
                                                   float* __restrict__ cs) {
    int w = (blockIdx.x << 2) | (threadIdx.x >> 6);   // global wave id [0, 8192)
    int lane = threadIdx.x & 63;
    int f = w & 63;
    int s = (w >> 6) & 31;
    int b = w >> 11;

    const float4* ep = (const float4*)emb + ((size_t)(b * F_ + f)) * (V_ / 4) + (s << 11);
    const unsigned short* mp = mask16 + (size_t)b * (V_ / 4) + (s << 11);

    float a0 = 0.f, a1 = 0.f, a2 = 0.f, a3 = 0.f;
    #pragma unroll
    for (int o = 0; o < 4; ++o) {
        float4 e[8];
        unsigned mm[8];
        #pragma unroll
        for (int i = 0; i < 8; ++i) e[i] = ep[(((o << 3) | i) << 6) | lane];
        #pragma unroll
        for (int i = 0; i < 8; ++i) mm[i] = mp[(((o << 3) | i) << 6) | lane];
        #pragma unroll
        for (int i = 0; i < 8; ++i) {
            unsigned m = mm[i];
            float4 ev = e[i];
            a0 += ( m        & 1u ? ev.x : 0.f) + ((m >>  4) & 1u ? ev.y : 0.f)
                + ((m >>  8) & 1u ? ev.z : 0.f) + ((m >> 12) & 1u ? ev.w : 0.f);
            a1 += ((m >>  1) & 1u ? ev.x : 0.f) + ((m >>  5) & 1u ? ev.y : 0.f)
                + ((m >>  9) & 1u ? ev.z : 0.f) + ((m >> 13) & 1u ? ev.w : 0.f);
            a2 += ((m >>  2) & 1u ? ev.x : 0.f) + ((m >>  6) & 1u ? ev.y : 0.f)
                + ((m >> 10) & 1u ? ev.z : 0.f) + ((m >> 14) & 1u ? ev.w : 0.f);
            a3 += ((m >>  3) & 1u ? ev.x : 0.f) + ((m >>  7) & 1u ? ev.y : 0.f)
                + ((m >> 11) & 1u ? ev.z : 0.f) + ((m >> 15) & 1u ? ev.w : 0.f);
        }
    }
    #pragma unroll
    for (int o = 1; o < 64; o <<= 1) {
        a0 += __shfl_xor(a0, o, 64);
        a1 += __shfl_xor(a1, o, 64);
        a2 += __shfl_xor(a2, o, 64);
        a3 += __shfl_xor(a3, o, 64);
    }
    float av = (lane == 0) ? a0 : (lane == 1) ? a1 : (lane == 2) ? a2 : a3;
    if (lane < 4) atomicAdd(&cs[lane * F_ + f], av);
}

__device__ __forceinline__ float weight_of(const float* __restrict__ p0, int v) {
    return ((p0[v] * p0[v + V_]) * p0[v + 2 * V_]) * p0[v + 3 * V_];
}

// level-1 histogram: top-8 bits of w; also materialize w bits for later passes
__global__ __launch_bounds__(256) void k_hist1(const float* __restrict__ proba,
                                               unsigned* __restrict__ hist1,
                                               unsigned* __restrict__ wbits) {
    __shared__ unsigned lh[256];
    int tid = threadIdx.x;
    lh[tid] = 0u;
    __syncthreads();
    int b = blockIdx.x >> 8;
    int base = (blockIdx.x & 255) << 10;
    const float* p0 = proba + (size_t)(b * C_) * V_;
    for (int it = 0; it < 4; ++it) {
        int v = base + tid + (it << 8);
        unsigned bits = __float_as_uint(weight_of(p0, v));
        wbits[(size_t)b * V_ + v] = bits;
        atomicAdd(&lh[bits >> 24], 1u);
    }
    __syncthreads();
    if (lh[tid]) atomicAdd(&hist1[b * 256 + tid], lh[tid]);
}

// level-2 histogram: next 8 bits, only for elements in bin T1 (reads wbits, 4 MB)
__global__ __launch_bounds__(256) void k_hist2(const unsigned* __restrict__ wbits,
                                               const unsigned* __restrict__ ctrl1,
                                               unsigned* __restrict__ hist2) {
    __shared__ unsigned lh[256];
    int tid = threadIdx.x;
    lh[tid] = 0u;
    __syncthreads();
    int b = blockIdx.x >> 8;
    int base = (blockIdx.x & 255) << 10;
    unsigned T1 = ctrl1[b * 2];
    for (int it = 0; it < 4; ++it) {
        int v = base + tid + (it << 8);
        unsigned bits = wbits[(size_t)b * V_ + v];
        if ((bits >> 24) == T1) atomicAdd(&lh[(bits >> 16) & 0xFF], 1u);
    }
    __syncthreads();
    if (lh[tid]) atomicAdd(&hist2[b * 256 + tid], lh[tid]);
}

// wave-parallel threshold finder over a 256-bin histogram (descending).
__global__ __launch_bounds__(256) void k_thresh(const unsigned* __restrict__ hist,
                                                const unsigned* __restrict__ ctrl_in,
                                                unsigned* __restrict__ ctrl_out,
                                                int lvl) {
    int b = threadIdx.x >> 6;
    int lane = threadIdx.x & 63;
    const unsigned* h = hist + b * 256;
    unsigned base = lvl ? ctrl_in[b * 2 + 1] : 0u;
    int binbase = 255 - 4 * lane;
    unsigned c0 = h[binbase], c1 = h[binbase - 1], c2 = h[binbase - 2], c3 = h[binbase - 3];
    unsigned cnt4 = c0 + c1 + c2 + c3;
    unsigned pref = cnt4;
    #pragma unroll
    for (int o = 1; o < 64; o <<= 1) {
        unsigned u = __shfl_up(pref, o, 64);
        if (lane >= o) pref += u;
    }
    unsigned above = base + pref - cnt4;
    unsigned t = above;
    int found = -1; unsigned nab = 0;
    if (t + c0 >= K_)                { found = binbase;     nab = t; }
    else if (t + c0 + c1 >= K_)      { found = binbase - 1; nab = t + c0; }
    else if (t + c0 + c1 + c2 >= K_) { found = binbase - 2; nab = t + c0 + c1; }
    else if (t + cnt4 >= K_)         { found = binbase - 3; nab = t + c0 + c1 + c2; }
    if (found >= 0 && above < K_) {
        ctrl_out[b * 2] = lvl ? ((ctrl_in[b * 2] << 8) | (unsigned)found) : (unsigned)found;
        ctrl_out[b * 2 + 1] = nab;
    }
}

// collect all candidates with (bits>>16) >= P16  (~K + one 16-bit bin)
__global__ __launch_bounds__(256) void k_collect(const unsigned* __restrict__ wbits,
                                                 const unsigned* __restrict__ ctrl2,
                                                 unsigned* __restrict__ ccount,
                                                 unsigned* __restrict__ cbits,
                                                 unsigned* __restrict__ cidx) {
    int b = blockIdx.x >> 8;
    int base = (blockIdx.x & 255) << 10;
    int tid = threadIdx.x;
    unsigned P16 = ctrl2[b * 2];
    for (int it = 0; it < 4; ++it) {
        int v = base + tid + (it << 8);
        unsigned bits = wbits[(size_t)b * V_ + v];
        if ((bits >> 16) >= P16) {
            unsigned pos = atomicAdd(&ccount[b], 1u);
            if (pos < CAP2) { cbits[b * CAP2 + pos] = bits; cidx[b * CAP2 + pos] = (unsigned)v; }
        }
    }
}

// exact top-K: one wave per b, lane-private LDS regions, zero barriers.
__global__ __launch_bounds__(64) void k_select(const unsigned* __restrict__ ccount,
                                               const unsigned* __restrict__ cbits,
                                               const unsigned* __restrict__ cidx,
                                               unsigned* __restrict__ idxout) {
    __shared__ ull keys[CAP2];
    int b = blockIdx.x;
    int lane = threadIdx.x;
    unsigned nc = ccount[b];
    int n = (int)(nc < CAP2 ? nc : CAP2);
    for (int i = lane; i < n; i += 64)
        keys[i] = ((ull)cbits[b * CAP2 + i] << 32) | (unsigned)(~cidx[b * CAP2 + i]);
    for (int k = 0; k < K_; ++k) {
        ull m = 0ull; int mslot = -1;
        for (int i = lane; i < n; i += 64) {
            ull key = keys[i];
            if (key > m) { m = key; mslot = i; }
        }
        ull lm = m;
        #pragma unroll
        for (int o = 1; o < 64; o <<= 1) {
            ull other = __shfl_xor(m, o, 64);
            if (other > m) m = other;
        }
        if (mslot >= 0 && lm == m) keys[mslot] = 0ull;
        if (lane == 0) idxout[b * K_ + k] = ~(unsigned)(m & 0xFFFFFFFFull);
    }
}

// final: one wave (64 lanes = F) per (b,k)
__global__ __launch_bounds__(64) void k_final(const float* __restrict__ emb,
                                              const int* __restrict__ y,
                                              const float* __restrict__ avg,
                                              const float* __restrict__ cs,
                                              const float* __restrict__ cnt,
                                              const unsigned* __restrict__ idxout,
                                              float* __restrict__ out) {
    int blk = blockIdx.x;
    int b = blk / K_;
    int k = blk % K_;
    int lane = threadIdx.x;
    unsigned v = idxout[b * K_ + k];

    float e = emb[((size_t)(b * F_ + lane)) * V_ + v];

    int y0v = y[((size_t)(b * C_ + 0)) * V_ + v];
    int y1v = y[((size_t)(b * C_ + 1)) * V_ + v];
    int y2v = y[((size_t)(b * C_ + 2)) * V_ + v];
    int y3v = y[((size_t)(b * C_ + 3)) * V_ + v];
    int cm = (y0v > 0) ? 0 : ((y1v > 0) ? 1 : ((y2v > 0) ? 2 : ((y3v > 0) ? 3 : 0)));
    float sel = (cm == 0) ? 1.f : 0.f;

    float t = e / TAU_;
    float ssum = 0.f;
    #pragma unroll
    for (int c = 1; c < 4; ++c) {
        float cc = cnt[c];
        float mean = cs[c * F_ + lane] / fmaxf(cc, 1.f);
        float av = avg[c * F_ + lane];
        float nar = (cc > 0.f) ? (av * (1.f - THETA) + mean * THETA) : av;
        ssum += expf(t * nar);
    }
    float term = -logf(ssum);
    #pragma unroll
    for (int o = 32; o > 0; o >>= 1) term += __shfl_down(term, o, 64);
    if (lane == 0) out[b * K_ + k] = term * sel;
}

extern "C" void kernel_launch(void* const* d_in, const int* in_sizes, int n_in,
                              void* d_out, int out_size, void* d_ws, size_t ws_size,
                              hipStream_t stream) {
    const float* proba = (const float*)d_in[0];
    const int* y = (const int*)d_in[1];
    const float* emb = (const float*)d_in[2];
    const float* avg = (const float*)d_in[3];
    float* out = (float*)d_out;

    char* ws = (char*)d_ws;
    float* cs = (float*)(ws + 0);
    float* cnt = (float*)(ws + 1024);
    unsigned* hist1 = (unsigned*)(ws + 2048);
    unsigned* hist2 = (unsigned*)(ws + 6144);
    unsigned* ctrl1 = (unsigned*)(ws + 10240);
    unsigned* ctrl2 = (unsigned*)(ws + 10272);
    unsigned* ccount = (unsigned*)(ws + 10304);
    unsigned* idxout = (unsigned*)(ws + 10368);
    unsigned* cbits = (unsigned*)(ws + 16384);
    unsigned* cidx = (unsigned*)(ws + 81920);
    unsigned* wbits = (unsigned*)(ws + 1048576);
    unsigned short* mask16 = (unsigned short*)(ws + 5242880);

    k_init<<<4, 256, 0, stream>>>(cs, cnt, hist1, hist2, ccount);
    k_mask<<<B_ * 256, 256, 0, stream>>>(y, mask16, cnt);
    k_class_sum<<<2048, 256, 0, stream>>>(emb, mask16, cs);
    k_hist1<<<B_ * 256, 256, 0, stream>>>(proba, hist1, wbits);
    k_thresh<<<1, 256, 0, stream>>>(hist1, nullptr, ctrl1, 0);
    k_hist2<<<B_ * 256, 256, 0, stream>>>(wbits, ctrl1, hist2);
    k_thresh<<<1, 256, 0, stream>>>(hist2, ctrl1, ctrl2, 1);
    k_collect<<<B_ * 256, 256, 0, stream>>>(wbits, ctrl2, ccount, cbits, cidx);
    k_select<<<B_, 64, 0, stream>>>(ccount, cbits, cidx, idxout);
    k_final<<<B_ * K_, 64, 0, stream>>>(emb, y, avg, cs, cnt, idxout, out);
}

// Round 7
// 162.998 us; speedup vs baseline: 2.2562x; 2.2562x over previous
//
#include <hip/hip_runtime.h>

#define B_ 4
#define C_ 4
#define V_ 262144
#define F_ 64
#define K_ 100
#define THETA 0.9f
#define TAU_ 0.1f
#define CAP2 4096

typedef unsigned long long ull;

// ---------------- workspace layout (bytes) ----------------
// cs     : 0       .. 1024     (C*F floats, [c][f])
// cnt    : 1024    .. 1040     (C floats)
// hist1  : 2048    .. 6144     (B*256 u32)
// hist2  : 6144    .. 10240    (B*256 u32)
// ctrl1  : 10240   .. 10272    (B*2 u32: T1, n_above)
// ctrl2  : 10272   .. 10304    (B*2 u32: P16, n_above2)
// ccount : 10304   .. 10320    (B u32)
// idxout : 10368   .. 11968    (B*K u32)
// cbits  : 16384   .. 81920    (B*CAP2 u32)
// cidx   : 81920   .. 147456   (B*CAP2 u32)
// cntp   : 147456  .. 163840   (1024*4 u32 — per-block count partials)
// wbits  : 1048576 .. 5242880  (B*V u32 — product weights' float bits)
// mask16 : 5242880 .. 5767168  (B*V/4 u16 — packed 4-bit class masks per float4)

__global__ void k_init(float* cs, unsigned* hist1, unsigned* hist2, unsigned* ccount) {
    int t = blockIdx.x * blockDim.x + threadIdx.x;
    if (t < C_ * F_) cs[t] = 0.f;
    if (t < B_ * 256) { hist1[t] = 0u; hist2[t] = 0u; }
    if (t < B_) ccount[t] = 0u;
}

// Pack y into 4-bit/v class masks (u16 per float4-group) + per-block count
// partials (NO same-address atomics — that was a 213us serialized-RMW chain).
__global__ __launch_bounds__(256) void k_mask(const int* __restrict__ y,
                                              unsigned short* __restrict__ mask16,
                                              unsigned* __restrict__ cntp) {
    __shared__ unsigned wc[4][2];
    int b = blockIdx.x >> 8;
    int i4 = ((blockIdx.x & 255) << 8) | threadIdx.x;   // float4-group in [0, V/4)
    int tid = threadIdx.x;
    int wave = tid >> 6, lane = tid & 63;

    const int4* y0 = (const int4*)(y + ((size_t)(b * C_ + 0)) * V_);
    const int4* y1 = (const int4*)(y + ((size_t)(b * C_ + 1)) * V_);
    const int4* y2 = (const int4*)(y + ((size_t)(b * C_ + 2)) * V_);
    const int4* y3 = (const int4*)(y + ((size_t)(b * C_ + 3)) * V_);
    int4 ya = y0[i4], yb = y1[i4], yc = y2[i4], yd = y3[i4];

    unsigned n0 = (unsigned)(ya.x > 0) | ((unsigned)(yb.x > 0) << 1) | ((unsigned)(yc.x > 0) << 2) | ((unsigned)(yd.x > 0) << 3);
    unsigned n1 = (unsigned)(ya.y > 0) | ((unsigned)(yb.y > 0) << 1) | ((unsigned)(yc.y > 0) << 2) | ((unsigned)(yd.y > 0) << 3);
    unsigned n2 = (unsigned)(ya.z > 0) | ((unsigned)(yb.z > 0) << 1) | ((unsigned)(yc.z > 0) << 2) | ((unsigned)(yd.z > 0) << 3);
    unsigned n3 = (unsigned)(ya.w > 0) | ((unsigned)(yb.w > 0) << 1) | ((unsigned)(yc.w > 0) << 2) | ((unsigned)(yd.w > 0) << 3);
    mask16[(size_t)b * (V_ / 4) + i4] = (unsigned short)(n0 | (n1 << 4) | (n2 << 8) | (n3 << 12));

    unsigned p01 = ((unsigned)(ya.x > 0) + (ya.y > 0) + (ya.z > 0) + (ya.w > 0))
                 | (((unsigned)(yb.x > 0) + (yb.y > 0) + (yb.z > 0) + (yb.w > 0)) << 16);
    unsigned p23 = ((unsigned)(yc.x > 0) + (yc.y > 0) + (yc.z > 0) + (yc.w > 0))
                 | (((unsigned)(yd.x > 0) + (yd.y > 0) + (yd.z > 0) + (yd.w > 0)) << 16);
    #pragma unroll
    for (int o = 1; o < 64; o <<= 1) {
        p01 += __shfl_xor(p01, o, 64);
        p23 += __shfl_xor(p23, o, 64);
    }
    if (lane == 0) { wc[wave][0] = p01; wc[wave][1] = p23; }
    __syncthreads();
    if (tid == 0) {
        unsigned q01 = wc[0][0] + wc[1][0] + wc[2][0] + wc[3][0];
        unsigned q23 = wc[0][1] + wc[1][1] + wc[2][1] + wc[3][1];
        unsigned* o4 = cntp + (blockIdx.x << 2);
        o4[0] = q01 & 0xFFFFu;
        o4[1] = q01 >> 16;
        o4[2] = q23 & 0xFFFFu;
        o4[3] = q23 >> 16;
    }
}

// reduce 1024x4 count partials -> cnt[4] floats. one block.
__global__ __launch_bounds__(256) void k_cnt(const unsigned* __restrict__ cntp,
                                             float* __restrict__ cnt) {
    __shared__ unsigned ws4[4][4];
    int tid = threadIdx.x;
    int wave = tid >> 6, lane = tid & 63;
    unsigned s0 = 0, s1 = 0, s2 = 0, s3 = 0;
    #pragma unroll
    for (int r = 0; r < 4; ++r) {
        const unsigned* p = cntp + (((r << 8) | tid) << 2);
        s0 += p[0]; s1 += p[1]; s2 += p[2]; s3 += p[3];
    }
    #pragma unroll
    for (int o = 1; o < 64; o <<= 1) {
        s0 += __shfl_xor(s0, o, 64);
        s1 += __shfl_xor(s1, o, 64);
        s2 += __shfl_xor(s2, o, 64);
        s3 += __shfl_xor(s3, o, 64);
    }
    if (lane == 0) { ws4[wave][0] = s0; ws4[wave][1] = s1; ws4[wave][2] = s2; ws4[wave][3] = s3; }
    __syncthreads();
    if (tid < 4) cnt[tid] = (float)(ws4[0][tid] + ws4[1][tid] + ws4[2][tid] + ws4[3][tid]);
}

// class_sum[c][f] += emb[b,f,v] * maskbit(c,v).
// One wave per (b, f, 8192-v segment): pure stream, per-thread accumulators,
// no LDS, no barriers, one shuffle-reduce + 4 spread atomics per wave.
__global__ __launch_bounds__(256) void k_class_sum(const float* __restrict__ emb,
                                                   const unsigned short* __restrict__ mask16,
                                                   float* __restrict__ cs) {
    int w = (blockIdx.x << 2) | (threadIdx.x >> 6);   // global wave id [0, 8192)
    int lane = threadIdx.x & 63;
    int f = w & 63;
    int s = (w >> 6) & 31;
    int b = w >> 11;

    const float4* ep = (const float4*)emb + ((size_t)(b * F_ + f)) * (V_ / 4) + (s << 11);
    const unsigned short* mp = mask16 + (size_t)b * (V_ / 4) + (s << 11);

    float a0 = 0.f, a1 = 0.f, a2 = 0.f, a3 = 0.f;
    #pragma unroll
    for (int o = 0; o < 4; ++o) {
        float4 e[8];
        unsigned mm[8];
        #pragma unroll
        for (int i = 0; i < 8; ++i) e[i] = ep[(((o << 3) | i) << 6) | lane];
        #pragma unroll
        for (int i = 0; i < 8; ++i) mm[i] = mp[(((o << 3) | i) << 6) | lane];
        #pragma unroll
        for (int i = 0; i < 8; ++i) {
            unsigned m = mm[i];
            float4 ev = e[i];
            a0 += ( m        & 1u ? ev.x : 0.f) + ((m >>  4) & 1u ? ev.y : 0.f)
                + ((m >>  8) & 1u ? ev.z : 0.f) + ((m >> 12) & 1u ? ev.w : 0.f);
            a1 += ((m >>  1) & 1u ? ev.x : 0.f) + ((m >>  5) & 1u ? ev.y : 0.f)
                + ((m >>  9) & 1u ? ev.z : 0.f) + ((m >> 13) & 1u ? ev.w : 0.f);
            a2 += ((m >>  2) & 1u ? ev.x : 0.f) + ((m >>  6) & 1u ? ev.y : 0.f)
                + ((m >> 10) & 1u ? ev.z : 0.f) + ((m >> 14) & 1u ? ev.w : 0.f);
            a3 += ((m >>  3) & 1u ? ev.x : 0.f) + ((m >>  7) & 1u ? ev.y : 0.f)
                + ((m >> 11) & 1u ? ev.z : 0.f) + ((m >> 15) & 1u ? ev.w : 0.f);
        }
    }
    #pragma unroll
    for (int o = 1; o < 64; o <<= 1) {
        a0 += __shfl_xor(a0, o, 64);
        a1 += __shfl_xor(a1, o, 64);
        a2 += __shfl_xor(a2, o, 64);
        a3 += __shfl_xor(a3, o, 64);
    }
    float av = (lane == 0) ? a0 : (lane == 1) ? a1 : (lane == 2) ? a2 : a3;
    if (lane < 4) atomicAdd(&cs[lane * F_ + f], av);
}

__device__ __forceinline__ float weight_of(const float* __restrict__ p0, int v) {
    return ((p0[v] * p0[v + V_]) * p0[v + 2 * V_]) * p0[v + 3 * V_];
}

// level-1 histogram: top-8 bits of w; also materialize w bits for later passes
__global__ __launch_bounds__(256) void k_hist1(const float* __restrict__ proba,
                                               unsigned* __restrict__ hist1,
                                               unsigned* __restrict__ wbits) {
    __shared__ unsigned lh[256];
    int tid = threadIdx.x;
    lh[tid] = 0u;
    __syncthreads();
    int b = blockIdx.x >> 8;
    int base = (blockIdx.x & 255) << 10;
    const float* p0 = proba + (size_t)(b * C_) * V_;
    for (int it = 0; it < 4; ++it) {
        int v = base + tid + (it << 8);
        unsigned bits = __float_as_uint(weight_of(p0, v));
        wbits[(size_t)b * V_ + v] = bits;
        atomicAdd(&lh[bits >> 24], 1u);
    }
    __syncthreads();
    if (lh[tid]) atomicAdd(&hist1[b * 256 + tid], lh[tid]);
}

// level-2 histogram: next 8 bits, only for elements in bin T1 (reads wbits, 4 MB)
__global__ __launch_bounds__(256) void k_hist2(const unsigned* __restrict__ wbits,
                                               const unsigned* __restrict__ ctrl1,
                                               unsigned* __restrict__ hist2) {
    __shared__ unsigned lh[256];
    int tid = threadIdx.x;
    lh[tid] = 0u;
    __syncthreads();
    int b = blockIdx.x >> 8;
    int base = (blockIdx.x & 255) << 10;
    unsigned T1 = ctrl1[b * 2];
    for (int it = 0; it < 4; ++it) {
        int v = base + tid + (it << 8);
        unsigned bits = wbits[(size_t)b * V_ + v];
        if ((bits >> 24) == T1) atomicAdd(&lh[(bits >> 16) & 0xFF], 1u);
    }
    __syncthreads();
    if (lh[tid]) atomicAdd(&hist2[b * 256 + tid], lh[tid]);
}

// wave-parallel threshold finder over a 256-bin histogram (descending).
__global__ __launch_bounds__(256) void k_thresh(const unsigned* __restrict__ hist,
                                                const unsigned* __restrict__ ctrl_in,
                                                unsigned* __restrict__ ctrl_out,
                                                int lvl) {
    int b = threadIdx.x >> 6;
    int lane = threadIdx.x & 63;
    const unsigned* h = hist + b * 256;
    unsigned base = lvl ? ctrl_in[b * 2 + 1] : 0u;
    int binbase = 255 - 4 * lane;
    unsigned c0 = h[binbase], c1 = h[binbase - 1], c2 = h[binbase - 2], c3 = h[binbase - 3];
    unsigned cnt4 = c0 + c1 + c2 + c3;
    unsigned pref = cnt4;
    #pragma unroll
    for (int o = 1; o < 64; o <<= 1) {
        unsigned u = __shfl_up(pref, o, 64);
        if (lane >= o) pref += u;
    }
    unsigned above = base + pref - cnt4;
    unsigned t = above;
    int found = -1; unsigned nab = 0;
    if (t + c0 >= K_)                { found = binbase;     nab = t; }
    else if (t + c0 + c1 >= K_)      { found = binbase - 1; nab = t + c0; }
    else if (t + c0 + c1 + c2 >= K_) { found = binbase - 2; nab = t + c0 + c1; }
    else if (t + cnt4 >= K_)         { found = binbase - 3; nab = t + c0 + c1 + c2; }
    if (found >= 0 && above < K_) {
        ctrl_out[b * 2] = lvl ? ((ctrl_in[b * 2] << 8) | (unsigned)found) : (unsigned)found;
        ctrl_out[b * 2 + 1] = nab;
    }
}

// collect all candidates with (bits>>16) >= P16  (~K + one 16-bit bin)
__global__ __launch_bounds__(256) void k_collect(const unsigned* __restrict__ wbits,
                                                 const unsigned* __restrict__ ctrl2,
                                                 unsigned* __restrict__ ccount,
                                                 unsigned* __restrict__ cbits,
                                                 unsigned* __restrict__ cidx) {
    int b = blockIdx.x >> 8;
    int base = (blockIdx.x & 255) << 10;
    int tid = threadIdx.x;
    unsigned P16 = ctrl2[b * 2];
    for (int it = 0; it < 4; ++it) {
        int v = base + tid + (it << 8);
        unsigned bits = wbits[(size_t)b * V_ + v];
        if ((bits >> 16) >= P16) {
            unsigned pos = atomicAdd(&ccount[b], 1u);
            if (pos < CAP2) { cbits[b * CAP2 + pos] = bits; cidx[b * CAP2 + pos] = (unsigned)v; }
        }
    }
}

// exact top-K: one wave per b, lane-private LDS regions, zero barriers.
__global__ __launch_bounds__(64) void k_select(const unsigned* __restrict__ ccount,
                                               const unsigned* __restrict__ cbits,
                                               const unsigned* __restrict__ cidx,
                                               unsigned* __restrict__ idxout) {
    __shared__ ull keys[CAP2];
    int b = blockIdx.x;
    int lane = threadIdx.x;
    unsigned nc = ccount[b];
    int n = (int)(nc < CAP2 ? nc : CAP2);
    for (int i = lane; i < n; i += 64)
        keys[i] = ((ull)cbits[b * CAP2 + i] << 32) | (unsigned)(~cidx[b * CAP2 + i]);
    for (int k = 0; k < K_; ++k) {
        ull m = 0ull; int mslot = -1;
        for (int i = lane; i < n; i += 64) {
            ull key = keys[i];
            if (key > m) { m = key; mslot = i; }
        }
        ull lm = m;
        #pragma unroll
        for (int o = 1; o < 64; o <<= 1) {
            ull other = __shfl_xor(m, o, 64);
            if (other > m) m = other;
        }
        if (mslot >= 0 && lm == m) keys[mslot] = 0ull;
        if (lane == 0) idxout[b * K_ + k] = ~(unsigned)(m & 0xFFFFFFFFull);
    }
}

// final: one wave (64 lanes = F) per (b,k)
__global__ __launch_bounds__(64) void k_final(const float* __restrict__ emb,
                                              const int* __restrict__ y,
                                              const float* __restrict__ avg,
                                              const float* __restrict__ cs,
                                              const float* __restrict__ cnt,
                                              const unsigned* __restrict__ idxout,
                                              float* __restrict__ out) {
    int blk = blockIdx.x;
    int b = blk / K_;
    int k = blk % K_;
    int lane = threadIdx.x;
    unsigned v = idxout[b * K_ + k];

    float e = emb[((size_t)(b * F_ + lane)) * V_ + v];

    int y0v = y[((size_t)(b * C_ + 0)) * V_ + v];
    int y1v = y[((size_t)(b * C_ + 1)) * V_ + v];
    int y2v = y[((size_t)(b * C_ + 2)) * V_ + v];
    int y3v = y[((size_t)(b * C_ + 3)) * V_ + v];
    int cm = (y0v > 0) ? 0 : ((y1v > 0) ? 1 : ((y2v > 0) ? 2 : ((y3v > 0) ? 3 : 0)));
    float sel = (cm == 0) ? 1.f : 0.f;

    float t = e / TAU_;
    float ssum = 0.f;
    #pragma unroll
    for (int c = 1; c < 4; ++c) {
        float cc = cnt[c];
        float mean = cs[c * F_ + lane] / fmaxf(cc, 1.f);
        float av = avg[c * F_ + lane];
        float nar = (cc > 0.f) ? (av * (1.f - THETA) + mean * THETA) : av;
        ssum += expf(t * nar);
    }
    float term = -logf(ssum);
    #pragma unroll
    for (int o = 32; o > 0; o >>= 1) term += __shfl_down(term, o, 64);
    if (lane == 0) out[b * K_ + k] = term * sel;
}

extern "C" void kernel_launch(void* const* d_in, const int* in_sizes, int n_in,
                              void* d_out, int out_size, void* d_ws, size_t ws_size,
                              hipStream_t stream) {
    const float* proba = (const float*)d_in[0];
    const int* y = (const int*)d_in[1];
    const float* emb = (const float*)d_in[2];
    const float* avg = (const float*)d_in[3];
    float* out = (float*)d_out;

    char* ws = (char*)d_ws;
    float* cs = (float*)(ws + 0);
    float* cnt = (float*)(ws + 1024);
    unsigned* hist1 = (unsigned*)(ws + 2048);
    unsigned* hist2 = (unsigned*)(ws + 6144);
    unsigned* ctrl1 = (unsigned*)(ws + 10240);
    unsigned* ctrl2 = (unsigned*)(ws + 10272);
    unsigned* ccount = (unsigned*)(ws + 10304);
    unsigned* idxout = (unsigned*)(ws + 10368);
    unsigned* cbits = (unsigned*)(ws + 16384);
    unsigned* cidx = (unsigned*)(ws + 81920);
    unsigned* cntp = (unsigned*)(ws + 147456);
    unsigned* wbits = (unsigned*)(ws + 1048576);
    unsigned short* mask16 = (unsigned short*)(ws + 5242880);

    k_init<<<4, 256, 0, stream>>>(cs, hist1, hist2, ccount);
    k_mask<<<B_ * 256, 256, 0, stream>>>(y, mask16, cntp);
    k_cnt<<<1, 256, 0, stream>>>(cntp, cnt);
    k_class_sum<<<2048, 256, 0, stream>>>(emb, mask16, cs);
    k_hist1<<<B_ * 256, 256, 0, stream>>>(proba, hist1, wbits);
    k_thresh<<<1, 256, 0, stream>>>(hist1, nullptr, ctrl1, 0);
    k_hist2<<<B_ * 256, 256, 0, stream>>>(wbits, ctrl1, hist2);
    k_thresh<<<1, 256, 0, stream>>>(hist2, ctrl1, ctrl2, 1);
    k_collect<<<B_ * 256, 256, 0, stream>>>(wbits, ctrl2, ccount, cbits, cidx);
    k_select<<<B_, 64, 0, stream>>>(ccount, cbits, cidx, idxout);
    k_final<<<B_ * K_, 64, 0, stream>>>(emb, y, avg, cs, cnt, idxout, out);
}

// Round 8
// 134.502 us; speedup vs baseline: 2.7342x; 1.2119x over previous
//
#include <hip/hip_runtime.h>

#define B_ 4
#define C_ 4
#define V_ 262144
#define F_ 64
#define K_ 100
#define THETA 0.9f
#define TAU_ 0.1f
#define CAP2 4096

typedef unsigned long long ull;

// ---------------- workspace layout (bytes) ----------------
// cs2    : 0       .. 8192     (8 replicas x C x F f32)
// cnt    : 8192    .. 8208     (C f32)
// ctrl1  : 8208    .. 8240     (B*2 u32: T1, n_above)
// ctrl2  : 8240    .. 8272     (B*2 u32: P16, n_above2)
// ccount : 8272    .. 8288     (B u32)
// idxout : 8320    .. 9920     (B*K u32)
// hist2  : 10240   .. 14336    (B*256 u32)
// cbits  : 16384   .. 81920    (B*CAP2 u32)
// cidx   : 81920   .. 147456   (B*CAP2 u32)
// cntp   : 147456  .. 163840   (1024*4 u32 per-block count partials)
// hist1p : 163840  .. 688128   (1024*256 u16 per-block hist1 partials)
// mask16 : 688128  .. 1212416  (B*V/4 u16 packed 4-bit class masks)
// wbits  : 1212416 .. 5406720  (B*V u32 product-weight float bits)

// Fused: init + y->mask16/count-partials + proba->wbits/hist1-partials.
// NO global atomics anywhere (round-6/7 lesson: same-address RMW chains
// cost ~125cy each; 1024-deep hist1 chains were ~50us hidden).
__global__ __launch_bounds__(256) void k_prep(const int* __restrict__ y,
                                              const float* __restrict__ proba,
                                              unsigned short* __restrict__ mask16,
                                              unsigned* __restrict__ cntp,
                                              unsigned short* __restrict__ hist1p,
                                              unsigned* __restrict__ wbits,
                                              float* __restrict__ cs2,
                                              unsigned* __restrict__ hist2,
                                              unsigned* __restrict__ ccount) {
    __shared__ unsigned lh[256];
    __shared__ unsigned wc[4][2];
    int blk = blockIdx.x;
    int tid = threadIdx.x;
    int wave = tid >> 6, lane = tid & 63;
    int b = blk >> 8;
    int i4 = ((blk & 255) << 8) | tid;   // float4-group in [0, V/4)

    lh[tid] = 0u;
    // folded init (arrays only consumed by LATER kernels -> no race)
    if (blk < 8) cs2[(blk << 8) | tid] = 0.f;
    else if (blk < 12) hist2[((blk - 8) << 8) | tid] = 0u;
    else if (blk == 12 && tid < 4) ccount[tid] = 0u;
    __syncthreads();

    // ---- y -> packed masks + per-block counts ----
    const int4* y0 = (const int4*)(y + ((size_t)(b * C_ + 0)) * V_);
    const int4* y1 = (const int4*)(y + ((size_t)(b * C_ + 1)) * V_);
    const int4* y2 = (const int4*)(y + ((size_t)(b * C_ + 2)) * V_);
    const int4* y3 = (const int4*)(y + ((size_t)(b * C_ + 3)) * V_);
    int4 ya = y0[i4], yb = y1[i4], yc = y2[i4], yd = y3[i4];

    unsigned n0 = (unsigned)(ya.x > 0) | ((unsigned)(yb.x > 0) << 1) | ((unsigned)(yc.x > 0) << 2) | ((unsigned)(yd.x > 0) << 3);
    unsigned n1 = (unsigned)(ya.y > 0) | ((unsigned)(yb.y > 0) << 1) | ((unsigned)(yc.y > 0) << 2) | ((unsigned)(yd.y > 0) << 3);
    unsigned n2 = (unsigned)(ya.z > 0) | ((unsigned)(yb.z > 0) << 1) | ((unsigned)(yc.z > 0) << 2) | ((unsigned)(yd.z > 0) << 3);
    unsigned n3 = (unsigned)(ya.w > 0) | ((unsigned)(yb.w > 0) << 1) | ((unsigned)(yc.w > 0) << 2) | ((unsigned)(yd.w > 0) << 3);
    mask16[(size_t)b * (V_ / 4) + i4] = (unsigned short)(n0 | (n1 << 4) | (n2 << 8) | (n3 << 12));

    unsigned p01 = ((unsigned)(ya.x > 0) + (ya.y > 0) + (ya.z > 0) + (ya.w > 0))
                 | (((unsigned)(yb.x > 0) + (yb.y > 0) + (yb.z > 0) + (yb.w > 0)) << 16);
    unsigned p23 = ((unsigned)(yc.x > 0) + (yc.y > 0) + (yc.z > 0) + (yc.w > 0))
                 | (((unsigned)(yd.x > 0) + (yd.y > 0) + (yd.z > 0) + (yd.w > 0)) << 16);
    #pragma unroll
    for (int o = 1; o < 64; o <<= 1) {
        p01 += __shfl_xor(p01, o, 64);
        p23 += __shfl_xor(p23, o, 64);
    }
    if (lane == 0) { wc[wave][0] = p01; wc[wave][1] = p23; }

    // ---- proba -> wbits + LDS hist1 ----
    const float* p0 = proba + (size_t)(b * C_) * V_;
    float4 qa = ((const float4*)p0)[i4];
    float4 qb = ((const float4*)(p0 + V_))[i4];
    float4 qc = ((const float4*)(p0 + 2 * V_))[i4];
    float4 qd = ((const float4*)(p0 + 3 * V_))[i4];
    uint4 wb;
    wb.x = __float_as_uint(((qa.x * qb.x) * qc.x) * qd.x);
    wb.y = __float_as_uint(((qa.y * qb.y) * qc.y) * qd.y);
    wb.z = __float_as_uint(((qa.z * qb.z) * qc.z) * qd.z);
    wb.w = __float_as_uint(((qa.w * qb.w) * qc.w) * qd.w);
    ((uint4*)wbits)[(size_t)b * (V_ / 4) + i4] = wb;
    atomicAdd(&lh[wb.x >> 24], 1u);
    atomicAdd(&lh[wb.y >> 24], 1u);
    atomicAdd(&lh[wb.z >> 24], 1u);
    atomicAdd(&lh[wb.w >> 24], 1u);
    __syncthreads();

    hist1p[(blk << 8) | tid] = (unsigned short)lh[tid];
    if (tid == 0) {
        unsigned q01 = wc[0][0] + wc[1][0] + wc[2][0] + wc[3][0];
        unsigned q23 = wc[0][1] + wc[1][1] + wc[2][1] + wc[3][1];
        unsigned* o4 = cntp + (blk << 2);
        o4[0] = q01 & 0xFFFFu; o4[1] = q01 >> 16;
        o4[2] = q23 & 0xFFFFu; o4[3] = q23 >> 16;
    }
}

// reduce hist1 partials + scan -> T1; block 0 also reduces cnt partials.
__global__ __launch_bounds__(256) void k_thresh0(const unsigned short* __restrict__ hist1p,
                                                 const unsigned* __restrict__ cntp,
                                                 unsigned* __restrict__ ctrl1,
                                                 float* __restrict__ cnt) {
    __shared__ unsigned bins[256];
    int b = blockIdx.x;
    int tid = threadIdx.x;
    int wave = tid >> 6, lane = tid & 63;
    unsigned s = 0;
    for (int c = 0; c < 256; ++c)
        s += hist1p[(((b << 8) | c) << 8) | tid];
    bins[tid] = s;
    __syncthreads();
    if (wave == 0) {
        int binbase = 255 - 4 * lane;
        unsigned c0 = bins[binbase], c1 = bins[binbase - 1], c2 = bins[binbase - 2], c3 = bins[binbase - 3];
        unsigned cnt4 = c0 + c1 + c2 + c3;
        unsigned pref = cnt4;
        #pragma unroll
        for (int o = 1; o < 64; o <<= 1) {
            unsigned u = __shfl_up(pref, o, 64);
            if (lane >= o) pref += u;
        }
        unsigned above = pref - cnt4;
        unsigned t = above;
        int found = -1; unsigned nab = 0;
        if (t + c0 >= K_)                { found = binbase;     nab = t; }
        else if (t + c0 + c1 >= K_)      { found = binbase - 1; nab = t + c0; }
        else if (t + c0 + c1 + c2 >= K_) { found = binbase - 2; nab = t + c0 + c1; }
        else if (t + cnt4 >= K_)         { found = binbase - 3; nab = t + c0 + c1 + c2; }
        if (found >= 0 && above < K_) {
            ctrl1[b * 2] = (unsigned)found;
            ctrl1[b * 2 + 1] = nab;
        }
    } else if (wave == 1 && b == 0) {
        unsigned s0 = 0, s1 = 0, s2 = 0, s3 = 0;
        #pragma unroll
        for (int r = 0; r < 16; ++r) {
            uint4 p = ((const uint4*)cntp)[(r << 6) | lane];
            s0 += p.x; s1 += p.y; s2 += p.z; s3 += p.w;
        }
        #pragma unroll
        for (int o = 1; o < 64; o <<= 1) {
            s0 += __shfl_xor(s0, o, 64);
            s1 += __shfl_xor(s1, o, 64);
            s2 += __shfl_xor(s2, o, 64);
            s3 += __shfl_xor(s3, o, 64);
        }
        if (lane == 0) {
            cnt[0] = (float)s0; cnt[1] = (float)s1;
            cnt[2] = (float)s2; cnt[3] = (float)s3;
        }
    }
}

// level-2 histogram: next 8 bits, only for elements in bin T1 (reads wbits)
__global__ __launch_bounds__(256) void k_hist2(const unsigned* __restrict__ wbits,
                                               const unsigned* __restrict__ ctrl1,
                                               unsigned* __restrict__ hist2) {
    __shared__ unsigned lh[256];
    int tid = threadIdx.x;
    lh[tid] = 0u;
    __syncthreads();
    int b = blockIdx.x >> 8;
    int base = (blockIdx.x & 255) << 10;
    unsigned T1 = ctrl1[b * 2];
    for (int it = 0; it < 4; ++it) {
        int v = base + tid + (it << 8);
        unsigned bits = wbits[(size_t)b * V_ + v];
        if ((bits >> 24) == T1) atomicAdd(&lh[(bits >> 16) & 0xFF], 1u);
    }
    __syncthreads();
    if (lh[tid]) atomicAdd(&hist2[b * 256 + tid], lh[tid]);  // sparse, shallow chains
}

// second-level threshold: P16 = (T1<<8)|T2
__global__ __launch_bounds__(256) void k_thresh1(const unsigned* __restrict__ hist,
                                                 const unsigned* __restrict__ ctrl_in,
                                                 unsigned* __restrict__ ctrl_out) {
    int b = threadIdx.x >> 6;
    int lane = threadIdx.x & 63;
    const unsigned* h = hist + b * 256;
    unsigned base = ctrl_in[b * 2 + 1];
    int binbase = 255 - 4 * lane;
    unsigned c0 = h[binbase], c1 = h[binbase - 1], c2 = h[binbase - 2], c3 = h[binbase - 3];
    unsigned cnt4 = c0 + c1 + c2 + c3;
    unsigned pref = cnt4;
    #pragma unroll
    for (int o = 1; o < 64; o <<= 1) {
        unsigned u = __shfl_up(pref, o, 64);
        if (lane >= o) pref += u;
    }
    unsigned above = base + pref - cnt4;
    unsigned t = above;
    int found = -1; unsigned nab = 0;
    if (t + c0 >= K_)                { found = binbase;     nab = t; }
    else if (t + c0 + c1 >= K_)      { found = binbase - 1; nab = t + c0; }
    else if (t + c0 + c1 + c2 >= K_) { found = binbase - 2; nab = t + c0 + c1; }
    else if (t + cnt4 >= K_)         { found = binbase - 3; nab = t + c0 + c1 + c2; }
    if (found >= 0 && above < K_) {
        ctrl_out[b * 2] = (ctrl_in[b * 2] << 8) | (unsigned)found;
        ctrl_out[b * 2 + 1] = nab;
    }
}

// collect all candidates with (bits>>16) >= P16
__global__ __launch_bounds__(256) void k_collect(const unsigned* __restrict__ wbits,
                                                 const unsigned* __restrict__ ctrl2,
                                                 unsigned* __restrict__ ccount,
                                                 unsigned* __restrict__ cbits,
                                                 unsigned* __restrict__ cidx) {
    int b = blockIdx.x >> 8;
    int base = (blockIdx.x & 255) << 10;
    int tid = threadIdx.x;
    unsigned P16 = ctrl2[b * 2];
    for (int it = 0; it < 4; ++it) {
        int v = base + tid + (it << 8);
        unsigned bits = wbits[(size_t)b * V_ + v];
        if ((bits >> 16) >= P16) {
            unsigned pos = atomicAdd(&ccount[b], 1u);
            if (pos < CAP2) { cbits[b * CAP2 + pos] = bits; cidx[b * CAP2 + pos] = (unsigned)v; }
        }
    }
}

// exact top-K: one wave per b, lane-private LDS regions, zero barriers.
__global__ __launch_bounds__(64) void k_select(const unsigned* __restrict__ ccount,
                                               const unsigned* __restrict__ cbits,
                                               const unsigned* __restrict__ cidx,
                                               unsigned* __restrict__ idxout) {
    __shared__ ull keys[CAP2];
    int b = blockIdx.x;
    int lane = threadIdx.x;
    unsigned nc = ccount[b];
    int n = (int)(nc < CAP2 ? nc : CAP2);
    for (int i = lane; i < n; i += 64)
        keys[i] = ((ull)cbits[b * CAP2 + i] << 32) | (unsigned)(~cidx[b * CAP2 + i]);
    for (int k = 0; k < K_; ++k) {
        ull m = 0ull; int mslot = -1;
        for (int i = lane; i < n; i += 64) {
            ull key = keys[i];
            if (key > m) { m = key; mslot = i; }
        }
        ull lm = m;
        #pragma unroll
        for (int o = 1; o < 64; o <<= 1) {
            ull other = __shfl_xor(m, o, 64);
            if (other > m) m = other;
        }
        if (mslot >= 0 && lm == m) keys[mslot] = 0ull;
        if (lane == 0) idxout[b * K_ + k] = ~(unsigned)(m & 0xFFFFFFFFull);
    }
}

// class_sum: pure stream; masks from LDS (staged once per block, coalesced);
// atomics spread over 8 cs replicas (chain 128 -> 16 per address).
__global__ __launch_bounds__(256) void k_class_sum(const float* __restrict__ emb,
                                                   const unsigned short* __restrict__ mask16,
                                                   float* __restrict__ cs2) {
    __shared__ unsigned short smask[2048];
    int blk = blockIdx.x;
    int tid = threadIdx.x;
    int wave = tid >> 6, lane = tid & 63;
    int b = blk >> 9;
    int rem = blk & 511;
    int fgrp = rem >> 5;
    int s = rem & 31;
    int f = (fgrp << 2) | wave;

    // stage 4KB of masks for (b, segment s): one uint4 per thread
    ((uint4*)smask)[tid] = ((const uint4*)(mask16 + (size_t)b * (V_ / 4) + (s << 11)))[tid];
    __syncthreads();

    const float4* ep = (const float4*)emb + ((size_t)((b << 6) | f)) * (V_ / 4) + (s << 11);

    float a0 = 0.f, a1 = 0.f, a2 = 0.f, a3 = 0.f;
    #pragma unroll
    for (int o = 0; o < 4; ++o) {
        float4 e[8];
        unsigned mm[8];
        #pragma unroll
        for (int i = 0; i < 8; ++i) e[i] = ep[(((o << 3) | i) << 6) | lane];
        #pragma unroll
        for (int i = 0; i < 8; ++i) mm[i] = smask[(((o << 3) | i) << 6) | lane];
        #pragma unroll
        for (int i = 0; i < 8; ++i) {
            unsigned m = mm[i];
            float4 ev = e[i];
            a0 += ( m        & 1u ? ev.x : 0.f) + ((m >>  4) & 1u ? ev.y : 0.f)
                + ((m >>  8) & 1u ? ev.z : 0.f) + ((m >> 12) & 1u ? ev.w : 0.f);
            a1 += ((m >>  1) & 1u ? ev.x : 0.f) + ((m >>  5) & 1u ? ev.y : 0.f)
                + ((m >>  9) & 1u ? ev.z : 0.f) + ((m >> 13) & 1u ? ev.w : 0.f);
            a2 += ((m >>  2) & 1u ? ev.x : 0.f) + ((m >>  6) & 1u ? ev.y : 0.f)
                + ((m >> 10) & 1u ? ev.z : 0.f) + ((m >> 14) & 1u ? ev.w : 0.f);
            a3 += ((m >>  3) & 1u ? ev.x : 0.f) + ((m >>  7) & 1u ? ev.y : 0.f)
                + ((m >> 11) & 1u ? ev.z : 0.f) + ((m >> 15) & 1u ? ev.w : 0.f);
        }
    }
    #pragma unroll
    for (int o = 1; o < 64; o <<= 1) {
        a0 += __shfl_xor(a0, o, 64);
        a1 += __shfl_xor(a1, o, 64);
        a2 += __shfl_xor(a2, o, 64);
        a3 += __shfl_xor(a3, o, 64);
    }
    float av = (lane == 0) ? a0 : (lane == 1) ? a1 : (lane == 2) ? a2 : a3;
    if (lane < 4) atomicAdd(&cs2[((blk & 7) << 8) | (lane << 6) | f], av);
}

// final: one wave (64 lanes = F) per (b,k); sums the 8 cs replicas inline.
__global__ __launch_bounds__(64) void k_final(const float* __restrict__ emb,
                                              const int* __restrict__ y,
                                              const float* __restrict__ avg,
                                              const float* __restrict__ cs2,
                                              const float* __restrict__ cnt,
                                              const unsigned* __restrict__ idxout,
                                              float* __restrict__ out) {
    int blk = blockIdx.x;
    int b = blk / K_;
    int k = blk % K_;
    int lane = threadIdx.x;
    unsigned v = idxout[b * K_ + k];

    float e = emb[((size_t)(b * F_ + lane)) * V_ + v];

    int y0v = y[((size_t)(b * C_ + 0)) * V_ + v];
    int y1v = y[((size_t)(b * C_ + 1)) * V_ + v];
    int y2v = y[((size_t)(b * C_ + 2)) * V_ + v];
    int y3v = y[((size_t)(b * C_ + 3)) * V_ + v];
    int cm = (y0v > 0) ? 0 : ((y1v > 0) ? 1 : ((y2v > 0) ? 2 : ((y3v > 0) ? 3 : 0)));
    float sel = (cm == 0) ? 1.f : 0.f;

    float t = e / TAU_;
    float ssum = 0.f;
    #pragma unroll
    for (int c = 1; c < 4; ++c) {
        float cc = cnt[c];
        float csum = 0.f;
        #pragma unroll
        for (int rep = 0; rep < 8; ++rep) csum += cs2[(rep << 8) | (c << 6) | lane];
        float mean = csum / fmaxf(cc, 1.f);
        float av = avg[c * F_ + lane];
        float nar = (cc > 0.f) ? (av * (1.f - THETA) + mean * THETA) : av;
        ssum += expf(t * nar);
    }
    float term = -logf(ssum);
    #pragma unroll
    for (int o = 32; o > 0; o >>= 1) term += __shfl_down(term, o, 64);
    if (lane == 0) out[b * K_ + k] = term * sel;
}

extern "C" void kernel_launch(void* const* d_in, const int* in_sizes, int n_in,
                              void* d_out, int out_size, void* d_ws, size_t ws_size,
                              hipStream_t stream) {
    const float* proba = (const float*)d_in[0];
    const int* y = (const int*)d_in[1];
    const float* emb = (const float*)d_in[2];
    const float* avg = (const float*)d_in[3];
    float* out = (float*)d_out;

    char* ws = (char*)d_ws;
    float* cs2 = (float*)(ws + 0);
    float* cnt = (float*)(ws + 8192);
    unsigned* ctrl1 = (unsigned*)(ws + 8208);
    unsigned* ctrl2 = (unsigned*)(ws + 8240);
    unsigned* ccount = (unsigned*)(ws + 8272);
    unsigned* idxout = (unsigned*)(ws + 8320);
    unsigned* hist2 = (unsigned*)(ws + 10240);
    unsigned* cbits = (unsigned*)(ws + 16384);
    unsigned* cidx = (unsigned*)(ws + 81920);
    unsigned* cntp = (unsigned*)(ws + 147456);
    unsigned short* hist1p = (unsigned short*)(ws + 163840);
    unsigned short* mask16 = (unsigned short*)(ws + 688128);
    unsigned* wbits = (unsigned*)(ws + 1212416);

    k_prep<<<B_ * 256, 256, 0, stream>>>(y, proba, mask16, cntp, hist1p, wbits, cs2, hist2, ccount);
    k_class_sum<<<2048, 256, 0, stream>>>(emb, mask16, cs2);
    k_thresh0<<<B_, 256, 0, stream>>>(hist1p, cntp, ctrl1, cnt);
    k_hist2<<<B_ * 256, 256, 0, stream>>>(wbits, ctrl1, hist2);
    k_thresh1<<<1, 256, 0, stream>>>(hist2, ctrl1, ctrl2);
    k_collect<<<B_ * 256, 256, 0, stream>>>(wbits, ctrl2, ccount, cbits, cidx);
    k_select<<<B_, 64, 0, stream>>>(ccount, cbits, cidx, idxout);
    k_final<<<B_ * K_, 64, 0, stream>>>(emb, y, avg, cs2, cnt, idxout, out);
}